// Round 1
// 84.105 us; speedup vs baseline: 1.0009x; 1.0009x over previous
//
#include <hip/hip_runtime.h>

constexpr int N  = 1024;
constexpr int BS = 32;
constexpr int FO = 128;

// workspace layout (floats)
constexpr int TAB_OFF  = 0;             // E table: [BS][N]
constexpr int SUMX_OFF = BS * N;        // sumX[BS]
constexpr int C12_OFF  = SUMX_OFF + BS; // {c1, c2}

// DPP-based wave64 sum, result broadcast to all lanes via readlane(63).
template <int ctrl, int rmask>
__device__ __forceinline__ float dpp_add(float x) {
  int y = __builtin_amdgcn_update_dpp(0, __float_as_int(x), ctrl, rmask, 0xf, true);
  return x + __int_as_float(y);
}

__device__ __forceinline__ float wave_sum_bcast(float x) {
  x = dpp_add<0x111, 0xf>(x);  // row_shr:1
  x = dpp_add<0x112, 0xf>(x);  // row_shr:2
  x = dpp_add<0x114, 0xf>(x);  // row_shr:4
  x = dpp_add<0x118, 0xf>(x);  // row_shr:8
  x = dpp_add<0x142, 0xa>(x);  // row_bcast:15
  x = dpp_add<0x143, 0xc>(x);  // row_bcast:31 -> lane63 = total
  return __int_as_float(__builtin_amdgcn_readlane(__float_as_int(x), 63));
}

// K1: per-(b,j) table E = exp(c2*x), per-batch sumX, and c1/c2 into ws.
// 32 blocks x 256 threads; each thread covers 4 consecutive j.
__global__ __launch_bounds__(256) void gat_prep(
    const float* __restrict__ x, const float* __restrict__ W,
    const float* __restrict__ a, float* __restrict__ ws) {
  const int b    = blockIdx.x;
  const int tid  = threadIdx.x;
  const int lane = tid & 63;

  // c1 = <W, a[0:128]>, c2 = <W, a[128:256]> — redundant per wave (~100 cyc)
  const float wl = W[lane], wh = W[lane + 64];
  const float c1 = wave_sum_bcast(wl * a[lane] + wh * a[lane + 64]);
  const float c2 = wave_sum_bcast(wl * a[FO + lane] + wh * a[FO + 64 + lane]);

  float4 xq = reinterpret_cast<const float4*>(x + (size_t)b * N)[tid];
  float4 e;
  e.x = __expf(c2 * xq.x);
  e.y = __expf(c2 * xq.y);
  e.z = __expf(c2 * xq.z);
  e.w = __expf(c2 * xq.w);
  reinterpret_cast<float4*>(ws + TAB_OFF)[b * (N / 4) + tid] = e;

  // per-batch sum of x for the empty-active-set fallback
  float s = wave_sum_bcast(xq.x + xq.y + xq.z + xq.w);
  __shared__ float ls[4];
  if (lane == 0) ls[tid >> 6] = s;
  __syncthreads();
  if (tid == 0) ws[SUMX_OFF + b] = ls[0] + ls[1] + ls[2] + ls[3];
  if (b == 0 && tid == 0) { ws[C12_OFF] = c1; ws[C12_OFF + 1] = c2; }
}

// K2: one wave per adjacency row i; blockIdx.y picks a group of 4 batches.
// Pair loop is exp-free: E_j comes from the ws table.
__global__ __launch_bounds__(64) void gat_main(
    const float* __restrict__ x, const int* __restrict__ adj,
    const float* __restrict__ W, const float* __restrict__ ws,
    float* __restrict__ out) {
  const int i    = blockIdx.x;
  const int lane = threadIdx.x;

  const float c1 = ws[C12_OFF];
  const float c2 = ws[C12_OFF + 1];

  // epilogue covers f = 2*lane, 2*lane+1 -> one float2 store per lane
  const float2 w2 = reinterpret_cast<const float2*>(W)[lane];

  // adjacency flags for j = 4*(lane + 64k) + m (coalesced int4 loads)
  float adjf[16];
  const int4* arow = reinterpret_cast<const int4*>(adj + (size_t)i * N);
#pragma unroll
  for (int k = 0; k < 4; ++k) {
    int4 aq = arow[lane + 64 * k];
    adjf[k * 4 + 0] = aq.x > 0 ? 1.f : 0.f;
    adjf[k * 4 + 1] = aq.y > 0 ? 1.f : 0.f;
    adjf[k * 4 + 2] = aq.z > 0 ? 1.f : 0.f;
    adjf[k * 4 + 3] = aq.w > 0 ? 1.f : 0.f;
  }

  const int b0 = blockIdx.y * (BS / 8);
#pragma unroll
  for (int b = b0; b < b0 + BS / 8; ++b) {
    const float* xb = x + b * N;
    const float thr = -c1 * xb[i];  // keep j iff c2*x_j > thr (and adj)
    float Z = 0.f, Wm = 0.f;
    const float4* xrow = reinterpret_cast<const float4*>(xb);
    const float4* Erow = reinterpret_cast<const float4*>(ws + TAB_OFF + (size_t)b * N);
#pragma unroll
    for (int k = 0; k < 4; ++k) {
      float4 xq = xrow[lane + 64 * k];
      float4 eq = Erow[lane + 64 * k];
      float xv[4] = {xq.x, xq.y, xq.z, xq.w};
      float ev[4] = {eq.x, eq.y, eq.z, eq.w};
#pragma unroll
      for (int m = 0; m < 4; ++m) {
        float w   = c2 * xv[m];
        float sel = (w > thr) ? (adjf[k * 4 + m] * ev[m]) : 0.f;
        Z += sel;
        Wm = fmaf(sel, xv[m], Wm);
      }
    }
    Z  = wave_sum_bcast(Z);
    Wm = wave_sum_bcast(Wm);
    // empty active set -> softmax over all-NEG row = uniform -> mean(x[b,:])
    float t = (Z > 0.f) ? (Wm / Z) : (ws[SUMX_OFF + b] * (1.f / N));

    // out[b,i,f] = elu(t * W[f])
    float z0 = t * w2.x, z1 = t * w2.y;
    float2 r;
    r.x = z0 > 0.f ? z0 : __expf(z0) - 1.f;
    r.y = z1 > 0.f ? z1 : __expf(z1) - 1.f;
    reinterpret_cast<float2*>(out + ((size_t)b * N + i) * FO)[lane] = r;
  }
}

extern "C" void kernel_launch(void* const* d_in, const int* in_sizes, int n_in,
                              void* d_out, int out_size, void* d_ws, size_t ws_size,
                              hipStream_t stream) {
  const float* x   = (const float*)d_in[0];
  const int*   adj = (const int*)d_in[1];
  const float* W   = (const float*)d_in[4];
  const float* a   = (const float*)d_in[5];
  float* ws  = (float*)d_ws;
  float* out = (float*)d_out;

  hipLaunchKernelGGL(gat_prep, dim3(BS), dim3(256), 0, stream, x, W, a, ws);
  hipLaunchKernelGGL(gat_main, dim3(N, 8), dim3(64), 0, stream,
                     x, adj, W, ws, out);
}